// Round 7
// baseline (60.160 us; speedup 1.0000x reference)
//
#include <hip/hip_runtime.h>

#define B_ 128
#define T_ 512
#define H_ 1024
#define K_ 7
#define START_ 5
#define STOP_ 6
#define LOG2E 1.4426950408889634f
#define LN2 0.6931471805599453f
#define NEG2 (-10000.0f * 1.4426950408889634f)   // -10000 * log2(e)
#define MS 57        // LDS matrix stride in floats (odd -> conflict-spread)
#define CHUNK 128    // timesteps per block
#define NCHUNK (B_ * T_ / CHUNK)   // 512 blocks
#define CWS 64       // ws floats per chunk: [49 mat][1 gold][pad]

typedef float f32x4 __attribute__((ext_vector_type(4)));

__device__ __forceinline__ float fexp2(float x) { return __builtin_amdgcn_exp2f(x); }
__device__ __forceinline__ float flog2(float x) { return __builtin_amdgcn_logf(x); }
__device__ __forceinline__ f32x4 ntload(const float* p) {
  return __builtin_nontemporal_load((const f32x4*)p);
}

// compute one row's 7 emissions from buffer R0..R3, store log2-scaled to LDS
#define COMPUTE_ROW(R0, R1, R2, R3, LR)                                         \
  do {                                                                          \
    float acc[8];                                                               \
    _Pragma("unroll") for (int k = 0; k < 8; ++k) acc[k] = 0.0f;                \
    _Pragma("unroll") for (int k = 0; k < K_; ++k) {                            \
      acc[k] += R0.x * w[k][0].x + R0.y * w[k][0].y + R0.z * w[k][0].z + R0.w * w[k][0].w; \
      acc[k] += R1.x * w[k][1].x + R1.y * w[k][1].y + R1.z * w[k][1].z + R1.w * w[k][1].w; \
      acc[k] += R2.x * w[k][2].x + R2.y * w[k][2].y + R2.z * w[k][2].z + R2.w * w[k][2].w; \
      acc[k] += R3.x * w[k][3].x + R3.y * w[k][3].y + R3.z * w[k][3].z + R3.w * w[k][3].w; \
    }                                                                           \
    const bool b0 = lane & 1;                                                   \
    float k0 = b0 ? acc[4] : acc[0], s0_ = b0 ? acc[0] : acc[4];                \
    float k1 = b0 ? acc[5] : acc[1], s1_ = b0 ? acc[1] : acc[5];                \
    float k2 = b0 ? acc[6] : acc[2], s2_ = b0 ? acc[2] : acc[6];                \
    float k3 = b0 ? acc[7] : acc[3], s3_ = b0 ? acc[3] : acc[7];                \
    k0 += __shfl_xor(s0_, 1, 64); k1 += __shfl_xor(s1_, 1, 64);                 \
    k2 += __shfl_xor(s2_, 1, 64); k3 += __shfl_xor(s3_, 1, 64);                 \
    const bool b1 = lane & 2;                                                   \
    float m0 = b1 ? k2 : k0, t0_ = b1 ? k0 : k2;                                \
    float m1 = b1 ? k3 : k1, t1_ = b1 ? k1 : k3;                                \
    m0 += __shfl_xor(t0_, 2, 64); m1 += __shfl_xor(t1_, 2, 64);                 \
    const bool b2 = lane & 4;                                                   \
    float x = b2 ? m1 : m0, y = b2 ? m0 : m1;                                   \
    x += __shfl_xor(y, 4, 64);                                                  \
    x += __shfl_xor(x, 8, 64);                                                  \
    x += __shfl_xor(x, 16, 64);                                                 \
    x += __shfl_xor(x, 32, 64);                                                 \
    if (lane < 8 && vidx < K_) ech[LR][vidx] = (x + myb) * LOG2E;               \
  } while (0)

#define LOAD_ROW(R0, R1, R2, R3, J)                                             \
  do {                                                                          \
    const float* p_ = features + (rowbase + (size_t)(J)) * H_ + lane * 4;       \
    R0 = ntload(p_); R1 = ntload(p_ + 256);                                     \
    R2 = ntload(p_ + 512); R3 = ntload(p_ + 768);                               \
  } while (0)

// tree-compose level (256 threads): NM outputs from 2*NM inputs in LDS
template <int NM>
__device__ __forceinline__ void level256(const float* __restrict__ evenB,
                                         const float* __restrict__ oddB,
                                         int qstride, float* __restrict__ dst,
                                         int tid) {
  constexpr int TOT = NM * 49;
  constexpr int NI = (TOT + 255) / 256;
  float tmp[NI];
#pragma unroll
  for (int i = 0; i < NI; ++i) {
    const int u = tid + i * 256;
    if (u < TOT) {
      const int q = u / 49, r = u - 49 * q, n = r / 7, p = r - 7 * n;
      const float* hi = oddB + q * qstride;
      const float* lo = evenB + q * qstride;
      float qq[7];
#pragma unroll
      for (int m = 0; m < 7; ++m) qq[m] = hi[n * 8 + m] + lo[m * 8 + p];
      float mx = fmaxf(fmaxf(fmaxf(qq[0], qq[1]), fmaxf(qq[2], qq[3])),
                       fmaxf(fmaxf(qq[4], qq[5]), qq[6]));
      float s = 0.f;
#pragma unroll
      for (int m = 0; m < 7; ++m) s += fexp2(qq[m] - mx);
      tmp[i] = mx + flog2(s);
    }
  }
  __syncthreads();
#pragma unroll
  for (int i = 0; i < NI; ++i) {
    const int u = tid + i * 256;
    if (u < TOT) {
      const int q = u / 49, r = u - 49 * q, n = r / 7, p = r - 7 * n;
      dst[q * MS + n * 8 + p] = tmp[i];
    }
  }
  __syncthreads();
}

// ---------------- Kernel 1: fused emissions + per-chunk scan ----------------
// 512 blocks; block = 128 consecutive timesteps of one batch. Emissions go to
// LDS only. Then pair-matrices (no-max lse, |vals|<~25) + 6 tree levels ->
// one 7x7 chunk matrix + gold partial to ws.
__global__ __launch_bounds__(256, 2) void fused_kernel(
    const float* __restrict__ features, const float* __restrict__ W,
    const float* __restrict__ bias, const int* __restrict__ tags,
    const int* __restrict__ lengths, const float* __restrict__ transitions,
    float* __restrict__ cws, float* __restrict__ out) {
  if (blockIdx.x == 0 && threadIdx.x == 0) out[0] = 0.0f;  // zero scalar output

  __shared__ float ech[CHUNK][8];    // 4 KB emissions (log2-scaled)
  __shared__ float s0[32 * MS];      // 7.3 KB even mats / tree ping
  __shared__ float s1[32 * MS];      // 7.3 KB odd mats / tree pong
  __shared__ float tr2s[49];
  __shared__ float gred[2];

  const int tid = threadIdx.x;
  const int lane = tid & 63;
  const int wv = tid >> 6;                 // wave 0..3
  const int chunk = blockIdx.x;            // 0..511
  const int b = chunk >> 2;                // batch
  const int cs = (chunk & 3) * CHUNK;      // chunk start time
  const int len = lengths[b];
  const size_t rowbase = (size_t)b * T_ + cs + wv * 32;

  if (tid < 49) tr2s[tid] = transitions[tid] * LOG2E;

  // ---- W fragment in registers (112 VGPRs) ----
  f32x4 w[K_][4];
#pragma unroll
  for (int k = 0; k < K_; ++k)
#pragma unroll
    for (int c = 0; c < 4; ++c)
      w[k][c] = *(const f32x4*)(W + k * H_ + c * 256 + lane * 4);

  const int vidx = ((lane & 1) << 2) | (lane & 2) | ((lane >> 2) & 1);
  float myb = 0.0f;
  if (vidx < K_) myb = bias[vidx];

  // ---- streaming phase: wave wv computes local rows wv*32 .. wv*32+31 ----
  f32x4 A0, A1, A2, A3, B0, B1, B2, B3, C0, C1, C2, C3;
  LOAD_ROW(A0, A1, A2, A3, 0);
  LOAD_ROW(B0, B1, B2, B3, 1);
  LOAD_ROW(C0, C1, C2, C3, 2);

  for (int jj = 0; jj < 9; ++jj) {
    const int j0 = 3 * jj;
    COMPUTE_ROW(A0, A1, A2, A3, wv * 32 + j0);
    LOAD_ROW(A0, A1, A2, A3, j0 + 3);
    COMPUTE_ROW(B0, B1, B2, B3, wv * 32 + j0 + 1);
    LOAD_ROW(B0, B1, B2, B3, j0 + 4);
    COMPUTE_ROW(C0, C1, C2, C3, wv * 32 + j0 + 2);
    LOAD_ROW(C0, C1, C2, C3, j0 + 5);
  }
  COMPUTE_ROW(A0, A1, A2, A3, wv * 32 + 27);
  LOAD_ROW(A0, A1, A2, A3, 30);
  COMPUTE_ROW(B0, B1, B2, B3, wv * 32 + 28);
  LOAD_ROW(B0, B1, B2, B3, 31);
  COMPUTE_ROW(C0, C1, C2, C3, wv * 32 + 29);
  COMPUTE_ROW(A0, A1, A2, A3, wv * 32 + 30);
  COMPUTE_ROW(B0, B1, B2, B3, wv * 32 + 31);
  __syncthreads();

  // ---- gold partial (threads 0..127, one local timestep each) ----
  const int* tg = tags + (size_t)b * T_;
  if (tid < CHUNK) {
    const int tglob = cs + tid;
    float gp = 0.f;
    if (tglob < len) {
      const int tag = tg[tglob];
      const int prev = tglob ? tg[tglob - 1] : START_;
      gp = ech[tid][tag] + tr2s[tag * 7 + prev];
    }
#pragma unroll
    for (int off = 32; off; off >>= 1) gp += __shfl_xor(gp, off, 64);
    if (lane == 0) gred[wv] = gp;
  }

  // ---- pair phase: 64 pair-matrices, entries spread over all 256 threads ----
  // P_q[n][p]: steps (cs+2q, cs+2q+1). no-max lse safe: |finite vals| <~ 25.
  {
    constexpr int TOT = 64 * 49;
    constexpr int NI = (TOT + 255) / 256;
#pragma unroll
    for (int i = 0; i < NI; ++i) {
      const int u = tid + i * 256;
      if (u < TOT) {
        const int q = u / 49, r = u - 49 * q, n = r / 7, p = r - 7 * n;
        const int lt0 = 2 * q, t0 = cs + lt0;
        float val;
        if (t0 + 1 < len) {
          float s = 1e-37f;
#pragma unroll
          for (int m = 0; m < 7; ++m)
            s += fexp2(tr2s[n * 7 + m] + ech[lt0][m] + tr2s[m * 7 + p]);
          val = ech[lt0 + 1][n] + flog2(s);
        } else if (t0 < len) {
          val = ech[lt0][n] + tr2s[n * 7 + p];
        } else {
          val = (n == p) ? 0.f : NEG2;
        }
        float* dstm = ((q & 1) ? s1 : s0) + (q >> 1) * MS;
        dstm[n * 8 + p] = val;
      }
    }
  }
  __syncthreads();

  // ---- tree: 64 -> 32 -> 16 -> 8 -> 4 -> 2 -> 1 ----
  level256<32>(s0, s1, MS, s0, tid);
  level256<16>(s0, s0 + MS, 2 * MS, s1, tid);
  level256<8>(s1, s1 + MS, 2 * MS, s0, tid);
  level256<4>(s0, s0 + MS, 2 * MS, s1, tid);
  level256<2>(s1, s1 + MS, 2 * MS, s0, tid);
  level256<1>(s0, s0 + MS, 2 * MS, s1, tid);   // final chunk matrix in s1

  // ---- emit chunk result: 49-float matrix + gold partial ----
  float* cw = cws + (size_t)chunk * CWS;
  if (tid < 49) cw[tid] = s1[(tid / 7) * 8 + (tid % 7)];
  if (tid == 49 + 0) cw[49] = gred[0] + gred[1];
}

// ---------------- Kernel 2: combine 4 chunk matrices per batch ----------------
// MAX-GUARDED lse here: chunk-product entries reach +-hundreds in log2 domain.
__global__ __launch_bounds__(64) void combine_kernel(
    const float* __restrict__ cws, const int* __restrict__ tags,
    const int* __restrict__ lengths, const float* __restrict__ transitions,
    float* __restrict__ out) {
  __shared__ float m01[49], m23[49], fin[49];
  const int tid = threadIdx.x;
  const int b = blockIdx.x;
  const float* base = cws + (size_t)b * 4 * CWS;
  const float* M0 = base;
  const float* M1 = base + CWS;
  const float* M2 = base + 2 * CWS;
  const float* M3 = base + 3 * CWS;

  const int n = tid / 7, p = tid % 7;
  if (tid < 49) {
    float qq[7], mx, s;
#pragma unroll
    for (int m = 0; m < 7; ++m) qq[m] = M1[n * 7 + m] + M0[m * 7 + p];
    mx = fmaxf(fmaxf(fmaxf(qq[0], qq[1]), fmaxf(qq[2], qq[3])),
               fmaxf(fmaxf(qq[4], qq[5]), qq[6]));
    s = 0.f;
#pragma unroll
    for (int m = 0; m < 7; ++m) s += fexp2(qq[m] - mx);
    m01[tid] = mx + flog2(s);
#pragma unroll
    for (int m = 0; m < 7; ++m) qq[m] = M3[n * 7 + m] + M2[m * 7 + p];
    mx = fmaxf(fmaxf(fmaxf(qq[0], qq[1]), fmaxf(qq[2], qq[3])),
               fmaxf(fmaxf(qq[4], qq[5]), qq[6]));
    s = 0.f;
#pragma unroll
    for (int m = 0; m < 7; ++m) s += fexp2(qq[m] - mx);
    m23[tid] = mx + flog2(s);
  }
  __syncthreads();
  if (tid < 49) {
    float qq[7];
#pragma unroll
    for (int m = 0; m < 7; ++m) qq[m] = m23[n * 7 + m] + m01[m * 7 + p];
    float mx = fmaxf(fmaxf(fmaxf(qq[0], qq[1]), fmaxf(qq[2], qq[3])),
                     fmaxf(fmaxf(qq[4], qq[5]), qq[6]));
    float s = 0.f;
#pragma unroll
    for (int m = 0; m < 7; ++m) s += fexp2(qq[m] - mx);
    fin[tid] = mx + flog2(s);
  }
  __syncthreads();

  if (tid == 0) {
    const int len = lengths[b];
    float tt[7];
#pragma unroll
    for (int nn = 0; nn < 7; ++nn)
      tt[nn] = fin[nn * 7 + START_] + transitions[STOP_ * 7 + nn] * LOG2E;
    float mx = tt[0];
#pragma unroll
    for (int nn = 1; nn < 7; ++nn) mx = fmaxf(mx, tt[nn]);
    float s = 0.f;
#pragma unroll
    for (int nn = 0; nn < 7; ++nn) s += fexp2(tt[nn] - mx);
    const float fwd = mx + flog2(s);
    const float gold = M0[49] + M1[49] + M2[49] + M3[49] +
                       transitions[STOP_ * 7 + tags[(size_t)b * T_ + len - 1]] * LOG2E;
    atomicAdd(out, (fwd - gold) * LN2);
  }
}

extern "C" void kernel_launch(void* const* d_in, const int* in_sizes, int n_in,
                              void* d_out, int out_size, void* d_ws, size_t ws_size,
                              hipStream_t stream) {
  const float* features    = (const float*)d_in[0];
  const int*   tags        = (const int*)d_in[1];
  const int*   lengths     = (const int*)d_in[2];
  const float* W           = (const float*)d_in[3];
  const float* bias        = (const float*)d_in[4];
  const float* transitions = (const float*)d_in[5];
  float* out = (float*)d_out;
  float* cws = (float*)d_ws;   // [512 chunks][64 floats] = 128 KB

  fused_kernel<<<NCHUNK, 256, 0, stream>>>(features, W, bias, tags, lengths,
                                           transitions, cws, out);
  combine_kernel<<<B_, 64, 0, stream>>>(cws, tags, lengths, transitions, out);
}

// Round 8
// 58.282 us; speedup vs baseline: 1.0322x; 1.0322x over previous
//
#include <hip/hip_runtime.h>

#define B_ 128
#define T_ 512
#define H_ 1024
#define K_ 7
#define START_ 5
#define STOP_ 6
#define LOG2E 1.4426950408889634f
#define LN2 0.6931471805599453f
#define NEG2 (-10000.0f * 1.4426950408889634f)   // -10000 * log2(e)
#define MS 57        // LDS matrix stride in floats (odd -> conflict-spread)
#define CHUNK 128    // timesteps per block
#define NCHUNK (B_ * T_ / CHUNK)   // 512 blocks
#define CWS 64       // ws floats per chunk: [49 mat][1 gold][pad]

typedef float f32x4 __attribute__((ext_vector_type(4)));
typedef float f32x2 __attribute__((ext_vector_type(2)));

__device__ __forceinline__ float fexp2(float x) { return __builtin_amdgcn_exp2f(x); }
__device__ __forceinline__ float flog2(float x) { return __builtin_amdgcn_logf(x); }
__device__ __forceinline__ f32x4 ntload(const float* p) {
  return __builtin_nontemporal_load((const f32x4*)p);
}

// cross-lane add via DPP (VALU pipe, no LDS): CTRL=0xB1 quad_perm xor1,
// 0x4E quad_perm xor2, 0x128 row_ror:8 == xor8 within 16-lane rows.
template <int CTRL>
__device__ __forceinline__ float dppf(float v) {
  return __int_as_float(
      __builtin_amdgcn_mov_dpp(__float_as_int(v), CTRL, 0xF, 0xF, false));
}

#define SVLO(R) __builtin_shufflevector(R, R, 0, 1)
#define SVHI(R) __builtin_shufflevector(R, R, 2, 3)

// compute one row's 7 emissions from buffer R0..R3, store log2-scaled to LDS.
// float2 math -> v_pk_fma_f32 (packed fp32, halves FMA issue count).
#define COMPUTE_ROW(R0, R1, R2, R3, LR)                                         \
  do {                                                                          \
    f32x2 acc2[8];                                                              \
    _Pragma("unroll") for (int k = 0; k < 8; ++k) acc2[k] = (f32x2){0.f, 0.f};  \
    _Pragma("unroll") for (int k = 0; k < K_; ++k) {                            \
      acc2[k] += SVLO(R0) * w2[k][0]; acc2[k] += SVHI(R0) * w2[k][1];           \
      acc2[k] += SVLO(R1) * w2[k][2]; acc2[k] += SVHI(R1) * w2[k][3];           \
      acc2[k] += SVLO(R2) * w2[k][4]; acc2[k] += SVHI(R2) * w2[k][5];           \
      acc2[k] += SVLO(R3) * w2[k][6]; acc2[k] += SVHI(R3) * w2[k][7];           \
    }                                                                           \
    float acc[8];                                                               \
    _Pragma("unroll") for (int k = 0; k < K_; ++k) acc[k] = acc2[k].x + acc2[k].y; \
    acc[7] = 0.f;                                                               \
    const bool b0 = lane & 1;                                                   \
    float k0 = b0 ? acc[4] : acc[0], s0_ = b0 ? acc[0] : acc[4];                \
    float k1 = b0 ? acc[5] : acc[1], s1_ = b0 ? acc[1] : acc[5];                \
    float k2 = b0 ? acc[6] : acc[2], s2_ = b0 ? acc[2] : acc[6];                \
    float k3 = b0 ? acc[7] : acc[3], s3_ = b0 ? acc[3] : acc[7];                \
    k0 += dppf<0xB1>(s0_); k1 += dppf<0xB1>(s1_);                               \
    k2 += dppf<0xB1>(s2_); k3 += dppf<0xB1>(s3_);                               \
    const bool b1 = lane & 2;                                                   \
    float m0 = b1 ? k2 : k0, t0_ = b1 ? k0 : k2;                                \
    float m1 = b1 ? k3 : k1, t1_ = b1 ? k1 : k3;                                \
    m0 += dppf<0x4E>(t0_); m1 += dppf<0x4E>(t1_);                               \
    const bool b2 = lane & 4;                                                   \
    float x = b2 ? m1 : m0, y = b2 ? m0 : m1;                                   \
    x += __shfl_xor(y, 4, 64);                                                  \
    x += dppf<0x128>(x);   /* xor8 via row_ror:8 */                             \
    x += __shfl_xor(x, 16, 64);                                                 \
    x += __shfl_xor(x, 32, 64);                                                 \
    if (lane < 8 && vidx < K_) ech[LR][vidx] = (x + myb) * LOG2E;               \
  } while (0)

#define LOAD_ROW(R0, R1, R2, R3, J)                                             \
  do {                                                                          \
    const float* p_ = features + (rowbase + (size_t)(J)) * H_ + lane * 4;       \
    R0 = ntload(p_); R1 = ntload(p_ + 256);                                     \
    R2 = ntload(p_ + 512); R3 = ntload(p_ + 768);                               \
  } while (0)

// tree-compose level (256 threads): NM outputs from 2*NM inputs in LDS
template <int NM>
__device__ __forceinline__ void level256(const float* __restrict__ evenB,
                                         const float* __restrict__ oddB,
                                         int qstride, float* __restrict__ dst,
                                         int tid) {
  constexpr int TOT = NM * 49;
  constexpr int NI = (TOT + 255) / 256;
  float tmp[NI];
#pragma unroll
  for (int i = 0; i < NI; ++i) {
    const int u = tid + i * 256;
    if (u < TOT) {
      const int q = u / 49, r = u - 49 * q, n = r / 7, p = r - 7 * n;
      const float* hi = oddB + q * qstride;
      const float* lo = evenB + q * qstride;
      float qq[7];
#pragma unroll
      for (int m = 0; m < 7; ++m) qq[m] = hi[n * 8 + m] + lo[m * 8 + p];
      float mx = fmaxf(fmaxf(fmaxf(qq[0], qq[1]), fmaxf(qq[2], qq[3])),
                       fmaxf(fmaxf(qq[4], qq[5]), qq[6]));
      float s = 0.f;
#pragma unroll
      for (int m = 0; m < 7; ++m) s += fexp2(qq[m] - mx);
      tmp[i] = mx + flog2(s);
    }
  }
  __syncthreads();
#pragma unroll
  for (int i = 0; i < NI; ++i) {
    const int u = tid + i * 256;
    if (u < TOT) {
      const int q = u / 49, r = u - 49 * q, n = r / 7, p = r - 7 * n;
      dst[q * MS + n * 8 + p] = tmp[i];
    }
  }
  __syncthreads();
}

// ---------------- Kernel 1: fused emissions + per-chunk scan ----------------
__global__ __launch_bounds__(256, 2) void fused_kernel(
    const float* __restrict__ features, const float* __restrict__ W,
    const float* __restrict__ bias, const int* __restrict__ tags,
    const int* __restrict__ lengths, const float* __restrict__ transitions,
    float* __restrict__ cws, float* __restrict__ out) {
  if (blockIdx.x == 0 && threadIdx.x == 0) out[0] = 0.0f;  // zero scalar output

  __shared__ float ech[CHUNK][8];    // 4 KB emissions (log2-scaled)
  __shared__ float s0[32 * MS];      // 7.3 KB even mats / tree ping
  __shared__ float s1[32 * MS];      // 7.3 KB odd mats / tree pong
  __shared__ float tr2s[49];
  __shared__ float gred[2];

  const int tid = threadIdx.x;
  const int lane = tid & 63;
  const int wv = tid >> 6;                 // wave 0..3
  const int chunk = blockIdx.x;            // 0..511
  const int b = chunk >> 2;                // batch
  const int cs = (chunk & 3) * CHUNK;      // chunk start time
  const int len = lengths[b];
  const size_t rowbase = (size_t)b * T_ + cs + wv * 32;

  if (tid < 49) tr2s[tid] = transitions[tid] * LOG2E;

  // ---- W fragment in registers as float2 pairs (112 VGPRs) ----
  // w2[k][2c+h] = W[k][c*256 + lane*4 + 2h .. +1]
  f32x2 w2[K_][8];
#pragma unroll
  for (int k = 0; k < K_; ++k)
#pragma unroll
    for (int c = 0; c < 4; ++c) {
      const f32x4 t = *(const f32x4*)(W + k * H_ + c * 256 + lane * 4);
      w2[k][2 * c] = SVLO(t);
      w2[k][2 * c + 1] = SVHI(t);
    }

  const int vidx = ((lane & 1) << 2) | (lane & 2) | ((lane >> 2) & 1);
  float myb = 0.0f;
  if (vidx < K_) myb = bias[vidx];

  // ---- streaming phase: wave wv computes local rows wv*32 .. wv*32+31 ----
  f32x4 A0, A1, A2, A3, B0, B1, B2, B3, C0, C1, C2, C3;
  LOAD_ROW(A0, A1, A2, A3, 0);
  LOAD_ROW(B0, B1, B2, B3, 1);
  LOAD_ROW(C0, C1, C2, C3, 2);

  for (int jj = 0; jj < 9; ++jj) {
    const int j0 = 3 * jj;
    COMPUTE_ROW(A0, A1, A2, A3, wv * 32 + j0);
    LOAD_ROW(A0, A1, A2, A3, j0 + 3);
    COMPUTE_ROW(B0, B1, B2, B3, wv * 32 + j0 + 1);
    LOAD_ROW(B0, B1, B2, B3, j0 + 4);
    COMPUTE_ROW(C0, C1, C2, C3, wv * 32 + j0 + 2);
    LOAD_ROW(C0, C1, C2, C3, j0 + 5);
  }
  COMPUTE_ROW(A0, A1, A2, A3, wv * 32 + 27);
  LOAD_ROW(A0, A1, A2, A3, 30);
  COMPUTE_ROW(B0, B1, B2, B3, wv * 32 + 28);
  LOAD_ROW(B0, B1, B2, B3, 31);
  COMPUTE_ROW(C0, C1, C2, C3, wv * 32 + 29);
  COMPUTE_ROW(A0, A1, A2, A3, wv * 32 + 30);
  COMPUTE_ROW(B0, B1, B2, B3, wv * 32 + 31);
  __syncthreads();

  // ---- gold partial (threads 0..127, one local timestep each) ----
  const int* tg = tags + (size_t)b * T_;
  if (tid < CHUNK) {
    const int tglob = cs + tid;
    float gp = 0.f;
    if (tglob < len) {
      const int tag = tg[tglob];
      const int prev = tglob ? tg[tglob - 1] : START_;
      gp = ech[tid][tag] + tr2s[tag * 7 + prev];
    }
#pragma unroll
    for (int off = 32; off; off >>= 1) gp += __shfl_xor(gp, off, 64);
    if (lane == 0) gred[wv] = gp;
  }

  // ---- pair phase: 64 pair-matrices, spread over all 256 threads ----
  {
    constexpr int TOT = 64 * 49;
    constexpr int NI = (TOT + 255) / 256;
#pragma unroll
    for (int i = 0; i < NI; ++i) {
      const int u = tid + i * 256;
      if (u < TOT) {
        const int q = u / 49, r = u - 49 * q, n = r / 7, p = r - 7 * n;
        const int lt0 = 2 * q, t0 = cs + lt0;
        float val;
        if (t0 + 1 < len) {
          float s = 1e-37f;
#pragma unroll
          for (int m = 0; m < 7; ++m)
            s += fexp2(tr2s[n * 7 + m] + ech[lt0][m] + tr2s[m * 7 + p]);
          val = ech[lt0 + 1][n] + flog2(s);
        } else if (t0 < len) {
          val = ech[lt0][n] + tr2s[n * 7 + p];
        } else {
          val = (n == p) ? 0.f : NEG2;
        }
        float* dstm = ((q & 1) ? s1 : s0) + (q >> 1) * MS;
        dstm[n * 8 + p] = val;
      }
    }
  }
  __syncthreads();

  // ---- tree: 64 -> 32 -> 16 -> 8 -> 4 -> 2 -> 1 ----
  level256<32>(s0, s1, MS, s0, tid);
  level256<16>(s0, s0 + MS, 2 * MS, s1, tid);
  level256<8>(s1, s1 + MS, 2 * MS, s0, tid);
  level256<4>(s0, s0 + MS, 2 * MS, s1, tid);
  level256<2>(s1, s1 + MS, 2 * MS, s0, tid);
  level256<1>(s0, s0 + MS, 2 * MS, s1, tid);   // final chunk matrix in s1

  // ---- emit chunk result: 49-float matrix + gold partial ----
  float* cw = cws + (size_t)chunk * CWS;
  if (tid < 49) cw[tid] = s1[(tid / 7) * 8 + (tid % 7)];
  if (tid == 49) cw[49] = gred[0] + gred[1];
}

// ---------------- Kernel 2: combine 4 chunk matrices per batch ----------------
__global__ __launch_bounds__(64) void combine_kernel(
    const float* __restrict__ cws, const int* __restrict__ tags,
    const int* __restrict__ lengths, const float* __restrict__ transitions,
    float* __restrict__ out) {
  __shared__ float m01[49], m23[49], fin[49];
  const int tid = threadIdx.x;
  const int b = blockIdx.x;
  const float* base = cws + (size_t)b * 4 * CWS;
  const float* M0 = base;
  const float* M1 = base + CWS;
  const float* M2 = base + 2 * CWS;
  const float* M3 = base + 3 * CWS;

  const int n = tid / 7, p = tid % 7;
  if (tid < 49) {
    float qq[7], mx, s;
#pragma unroll
    for (int m = 0; m < 7; ++m) qq[m] = M1[n * 7 + m] + M0[m * 7 + p];
    mx = fmaxf(fmaxf(fmaxf(qq[0], qq[1]), fmaxf(qq[2], qq[3])),
               fmaxf(fmaxf(qq[4], qq[5]), qq[6]));
    s = 0.f;
#pragma unroll
    for (int m = 0; m < 7; ++m) s += fexp2(qq[m] - mx);
    m01[tid] = mx + flog2(s);
#pragma unroll
    for (int m = 0; m < 7; ++m) qq[m] = M3[n * 7 + m] + M2[m * 7 + p];
    mx = fmaxf(fmaxf(fmaxf(qq[0], qq[1]), fmaxf(qq[2], qq[3])),
               fmaxf(fmaxf(qq[4], qq[5]), qq[6]));
    s = 0.f;
#pragma unroll
    for (int m = 0; m < 7; ++m) s += fexp2(qq[m] - mx);
    m23[tid] = mx + flog2(s);
  }
  __syncthreads();
  if (tid < 49) {
    float qq[7];
#pragma unroll
    for (int m = 0; m < 7; ++m) qq[m] = m23[n * 7 + m] + m01[m * 7 + p];
    float mx = fmaxf(fmaxf(fmaxf(qq[0], qq[1]), fmaxf(qq[2], qq[3])),
                     fmaxf(fmaxf(qq[4], qq[5]), qq[6]));
    float s = 0.f;
#pragma unroll
    for (int m = 0; m < 7; ++m) s += fexp2(qq[m] - mx);
    fin[tid] = mx + flog2(s);
  }
  __syncthreads();

  if (tid == 0) {
    const int len = lengths[b];
    float tt[7];
#pragma unroll
    for (int nn = 0; nn < 7; ++nn)
      tt[nn] = fin[nn * 7 + START_] + transitions[STOP_ * 7 + nn] * LOG2E;
    float mx = tt[0];
#pragma unroll
    for (int nn = 1; nn < 7; ++nn) mx = fmaxf(mx, tt[nn]);
    float s = 0.f;
#pragma unroll
    for (int nn = 0; nn < 7; ++nn) s += fexp2(tt[nn] - mx);
    const float fwd = mx + flog2(s);
    const float gold = M0[49] + M1[49] + M2[49] + M3[49] +
                       transitions[STOP_ * 7 + tags[(size_t)b * T_ + len - 1]] * LOG2E;
    atomicAdd(out, (fwd - gold) * LN2);
  }
}

extern "C" void kernel_launch(void* const* d_in, const int* in_sizes, int n_in,
                              void* d_out, int out_size, void* d_ws, size_t ws_size,
                              hipStream_t stream) {
  const float* features    = (const float*)d_in[0];
  const int*   tags        = (const int*)d_in[1];
  const int*   lengths     = (const int*)d_in[2];
  const float* W           = (const float*)d_in[3];
  const float* bias        = (const float*)d_in[4];
  const float* transitions = (const float*)d_in[5];
  float* out = (float*)d_out;
  float* cws = (float*)d_ws;   // [512 chunks][64 floats] = 128 KB

  fused_kernel<<<NCHUNK, 256, 0, stream>>>(features, W, bias, tags, lengths,
                                           transitions, cws, out);
  combine_kernel<<<B_, 64, 0, stream>>>(cws, tags, lengths, transitions, out);
}